// Round 8
// baseline (190.598 us; speedup 1.0000x reference)
//
#include <hip/hip_runtime.h>
#include <math.h>

#define N_NODES 100000
#define N_EDGES 1600000
#define NBUK 196          // dst>>9 -> 0..195 (512 nodes per bucket)
#define BCAP 16000        // entries per bucket region (mean 8192)
#define BINCHUNK 4096     // edges per k_bin block (256 thr x 16)

typedef unsigned short u16;
typedef u16 u16x4 __attribute__((ext_vector_type(4)));
typedef u16 u16x8 __attribute__((ext_vector_type(8)));
typedef short s16x8 __attribute__((ext_vector_type(8)));
typedef float f32x4 __attribute__((ext_vector_type(4)));

__device__ __forceinline__ float bf2f(u16 u) {
    union { unsigned i; float f; } v; v.i = ((unsigned)u) << 16; return v.f;
}
__device__ __forceinline__ u16 f2bf(float f) {
    union { float f; unsigned i; } v; v.f = f;
    return (u16)((v.i + 0x7FFFu + ((v.i >> 16) & 1u)) >> 16);  // RNE
}

// ---------------------------------------------------------------- binning ---
__global__ __launch_bounds__(256) void k_bin(const int* __restrict__ src,
                                             const int* __restrict__ dst,
                                             int* bucketCursor,
                                             unsigned int* __restrict__ bins) {
    __shared__ int lcnt[NBUK];
    __shared__ int lbase[NBUK];
    const int t = threadIdx.x;
    if (t < NBUK) lcnt[t] = 0;
    __syncthreads();

    const int e0 = blockIdx.x * BINCHUNK + t * 16;
    int4 s4[4], d4[4];
    int bkt[16], rnk[16];
    const bool valid = e0 < N_EDGES;   // N_EDGES % 16 == 0
    if (valid) {
        #pragma unroll
        for (int k = 0; k < 4; ++k) {
            s4[k] = *(const int4*)(src + e0 + 4 * k);
            d4[k] = *(const int4*)(dst + e0 + 4 * k);
        }
        #pragma unroll
        for (int k = 0; k < 4; ++k) {
            int dd[4] = { d4[k].x, d4[k].y, d4[k].z, d4[k].w };
            #pragma unroll
            for (int j = 0; j < 4; ++j) {
                int b = dd[j] >> 9;
                bkt[4 * k + j] = b;
                rnk[4 * k + j] = atomicAdd(&lcnt[b], 1);
            }
        }
    }
    __syncthreads();
    if (t < NBUK && lcnt[t] > 0) lbase[t] = atomicAdd(&bucketCursor[t], lcnt[t]);
    __syncthreads();
    if (valid) {
        #pragma unroll
        for (int k = 0; k < 4; ++k) {
            int ss[4] = { s4[k].x, s4[k].y, s4[k].z, s4[k].w };
            int dd[4] = { d4[k].x, d4[k].y, d4[k].z, d4[k].w };
            #pragma unroll
            for (int j = 0; j < 4; ++j) {
                int i = 4 * k + j;
                unsigned w = ((unsigned)(dd[j] & 511) << 17) | (unsigned)ss[j];
                bins[(size_t)bkt[i] * BCAP + lbase[bkt[i]] + rnk[i]] = w;
            }
        }
    }
}

// ------------------------------------------------- bucket-total scan (1 wg) -
__global__ __launch_bounds__(256) void k_bscan(const int* __restrict__ bucketCursor,
                                               int* __restrict__ gBase,
                                               int* __restrict__ row_start) {
    __shared__ int sd[256];
    const int t = threadIdx.x;
    int v = (t < NBUK) ? bucketCursor[t] : 0;
    sd[t] = v;
    __syncthreads();
    #pragma unroll
    for (int off = 1; off < 256; off <<= 1) {
        int x = (t >= off) ? sd[t - off] : 0;
        __syncthreads();
        sd[t] += x;
        __syncthreads();
    }
    if (t < NBUK) gBase[t] = (t > 0) ? sd[t - 1] : 0;
    if (t == 0) row_start[N_NODES] = N_EDGES;
}

// ------------------------------------------- per-bucket CSR build -----------
__global__ __launch_bounds__(256) void k_build(const unsigned int* __restrict__ bins,
                                               const int* __restrict__ bucketCursor,
                                               const int* __restrict__ gBase,
                                               int* __restrict__ row_start,
                                               float* __restrict__ dinv,
                                               int* __restrict__ csr_src) {
    __shared__ int cnt[512];
    __shared__ int psum[256];
    __shared__ int cur[512];
    const int b = blockIdx.x;
    const int t = threadIdx.x;
    const int bcnt = bucketCursor[b];
    const int gb = gBase[b];
    const unsigned int* mybins = bins + (size_t)b * BCAP;

    cnt[t] = 0; cnt[t + 256] = 0;
    __syncthreads();
    for (int i = t; i < bcnt; i += 256) {
        unsigned w = mybins[i];
        atomicAdd(&cnt[w >> 17], 1);
    }
    __syncthreads();
    int c0 = cnt[2 * t], c1 = cnt[2 * t + 1];
    psum[t] = c0 + c1;
    __syncthreads();
    #pragma unroll
    for (int off = 1; off < 256; off <<= 1) {
        int x = (t >= off) ? psum[t - off] : 0;
        __syncthreads();
        psum[t] += x;
        __syncthreads();
    }
    int exclPair = (t > 0) ? psum[t - 1] : 0;
    int o0 = exclPair, o1 = exclPair + c0;
    cur[2 * t] = o0; cur[2 * t + 1] = o1;
    const int nb = b << 9;
    if (nb + 2 * t < N_NODES) {
        row_start[nb + 2 * t] = gb + o0;
        dinv[nb + 2 * t] = rsqrtf((float)(c0 + 1));
    }
    if (nb + 2 * t + 1 < N_NODES) {
        row_start[nb + 2 * t + 1] = gb + o1;
        dinv[nb + 2 * t + 1] = rsqrtf((float)(c1 + 1));
    }
    __syncthreads();
    for (int i = t; i < bcnt; i += 256) {
        unsigned w = mybins[i];
        int dl = w >> 17;
        int s = (int)(w & 0x1FFFFu);
        int p = atomicAdd(&cur[dl], 1);
        csr_src[gb + p] = s;
    }
}

// ------------------------------------------------------- GEMM1 (MFMA) -------
// C = (x @ W1) * dinv via hi/lo bf16 split. Rows >= N_NODES get zeros (the
// aggregate's dummy-gather zero row lives at row N_NODES).
__global__ __launch_bounds__(256) void k_gemm1(const float* __restrict__ X,
                                               const float* __restrict__ W,
                                               const float* __restrict__ dinv,
                                               u16* __restrict__ H) {
    __shared__ u16 sxh[64 * 128];
    __shared__ u16 sxl[64 * 128];
    __shared__ u16 wth[64 * 128];
    __shared__ u16 wtl[64 * 128];
    const int t = threadIdx.x;
    const int blk = blockIdx.x;

    {
        const float4* Xv = (const float4*)X;
        #pragma unroll
        for (int i = 0; i < 8; ++i) {
            int idx = i * 256 + t;
            int row = idx >> 5;
            int k4  = (idx & 31) << 2;
            int grow = blk * 64 + row;
            float4 v = make_float4(0.f, 0.f, 0.f, 0.f);
            if (grow < N_NODES) v = Xv[(size_t)grow * 32 + (idx & 31)];
            float f[4] = { v.x, v.y, v.z, v.w };
            u16x4 hv, lv;
            #pragma unroll
            for (int j = 0; j < 4; ++j) {
                u16 h = f2bf(f[j]);
                hv[j] = h;
                lv[j] = f2bf(f[j] - bf2f(h));
            }
            int byte = (row * 256 + k4 * 2) ^ ((row & 7) << 4);
            *(u16x4*)((char*)sxh + byte) = hv;
            *(u16x4*)((char*)sxl + byte) = lv;
        }
    }
    {
        const float4* Wv = (const float4*)W;
        #pragma unroll
        for (int i = 0; i < 8; ++i) {
            int idx = i * 256 + t;
            int k  = idx >> 4;
            int c0 = (idx & 15) << 2;
            float4 v = Wv[idx];
            float f[4] = { v.x, v.y, v.z, v.w };
            #pragma unroll
            for (int j = 0; j < 4; ++j) {
                int c = c0 + j;
                int byte = (c * 256 + k * 2) ^ ((c & 7) << 4);
                u16 h = f2bf(f[j]);
                *(u16*)((char*)wth + byte) = h;
                *(u16*)((char*)wtl + byte) = f2bf(f[j] - bf2f(h));
            }
        }
    }
    __syncthreads();

    const int lane = t & 63;
    const int w    = t >> 6;
    const int l16  = lane & 15;
    const int kg   = lane >> 4;
    f32x4 acc[4];
    #pragma unroll
    for (int nt = 0; nt < 4; ++nt)
        #pragma unroll
        for (int j = 0; j < 4; ++j) acc[nt][j] = 0.f;

    const int arow = w * 16 + l16;
    const int aswz = (arow & 7) << 4;
    #pragma unroll
    for (int kt = 0; kt < 4; ++kt) {
        const int koff = kt * 64 + kg * 16;
        s16x8 ah = *(const s16x8*)((const char*)sxh + ((arow * 256 + koff) ^ aswz));
        s16x8 al = *(const s16x8*)((const char*)sxl + ((arow * 256 + koff) ^ aswz));
        #pragma unroll
        for (int nt = 0; nt < 4; ++nt) {
            const int c = nt * 16 + l16;
            const int wb = (c * 256 + koff) ^ ((c & 7) << 4);
            s16x8 bh = *(const s16x8*)((const char*)wth + wb);
            s16x8 bl = *(const s16x8*)((const char*)wtl + wb);
            acc[nt] = __builtin_amdgcn_mfma_f32_16x16x32_bf16(ah, bh, acc[nt], 0, 0, 0);
            acc[nt] = __builtin_amdgcn_mfma_f32_16x16x32_bf16(ah, bl, acc[nt], 0, 0, 0);
            acc[nt] = __builtin_amdgcn_mfma_f32_16x16x32_bf16(al, bh, acc[nt], 0, 0, 0);
        }
    }
    const int rbase = blk * 64 + w * 16 + kg * 4;
    #pragma unroll
    for (int reg = 0; reg < 4; ++reg) {
        int row = rbase + reg;
        float di = (row < N_NODES) ? dinv[row] : 0.f;
        #pragma unroll
        for (int nt = 0; nt < 4; ++nt)
            H[(size_t)row * 64 + nt * 16 + l16] = f2bf(acc[nt][reg] * di);
    }
}

// ------------------------------------------------------- GEMM2 (MFMA) -------
__global__ __launch_bounds__(256) void k_gemm2(const u16* __restrict__ Xb,
                                               const float* __restrict__ W,
                                               const float* __restrict__ dinv,
                                               u16* __restrict__ H) {
    __shared__ u16 sxb[64 * 64];
    __shared__ u16 wth[64 * 64];
    __shared__ u16 wtl[64 * 64];
    const int t = threadIdx.x;
    const int blk = blockIdx.x;

    {
        const u16x8* Xv = (const u16x8*)Xb;
        #pragma unroll
        for (int i = 0; i < 2; ++i) {
            int idx = i * 256 + t;
            int row = idx >> 3;
            int k0  = (idx & 7) << 3;
            int grow = blk * 64 + row;
            u16x8 v;
            #pragma unroll
            for (int j = 0; j < 8; ++j) v[j] = 0;
            if (grow < N_NODES) v = Xv[(size_t)grow * 8 + (idx & 7)];
            int byte = (row * 128 + k0 * 2) ^ ((row & 7) << 4);
            *(u16x8*)((char*)sxb + byte) = v;
        }
    }
    {
        const float4* Wv = (const float4*)W;
        #pragma unroll
        for (int i = 0; i < 4; ++i) {
            int idx = i * 256 + t;
            int k  = idx >> 4;
            int c0 = (idx & 15) << 2;
            float4 v = Wv[idx];
            float f[4] = { v.x, v.y, v.z, v.w };
            #pragma unroll
            for (int j = 0; j < 4; ++j) {
                int c = c0 + j;
                int byte = (c * 128 + k * 2) ^ ((c & 7) << 4);
                u16 h = f2bf(f[j]);
                *(u16*)((char*)wth + byte) = h;
                *(u16*)((char*)wtl + byte) = f2bf(f[j] - bf2f(h));
            }
        }
    }
    __syncthreads();

    const int lane = t & 63;
    const int w    = t >> 6;
    const int l16  = lane & 15;
    const int kg   = lane >> 4;
    f32x4 acc[4];
    #pragma unroll
    for (int nt = 0; nt < 4; ++nt)
        #pragma unroll
        for (int j = 0; j < 4; ++j) acc[nt][j] = 0.f;

    const int arow = w * 16 + l16;
    const int aswz = (arow & 7) << 4;
    #pragma unroll
    for (int kt = 0; kt < 2; ++kt) {
        const int koff = kt * 64 + kg * 16;
        s16x8 a = *(const s16x8*)((const char*)sxb + ((arow * 128 + koff) ^ aswz));
        #pragma unroll
        for (int nt = 0; nt < 4; ++nt) {
            const int c = nt * 16 + l16;
            const int wb = (c * 128 + koff) ^ ((c & 7) << 4);
            s16x8 bh = *(const s16x8*)((const char*)wth + wb);
            s16x8 bl = *(const s16x8*)((const char*)wtl + wb);
            acc[nt] = __builtin_amdgcn_mfma_f32_16x16x32_bf16(a, bh, acc[nt], 0, 0, 0);
            acc[nt] = __builtin_amdgcn_mfma_f32_16x16x32_bf16(a, bl, acc[nt], 0, 0, 0);
        }
    }
    const int rbase = blk * 64 + w * 16 + kg * 4;
    #pragma unroll
    for (int reg = 0; reg < 4; ++reg) {
        int row = rbase + reg;
        float di = (row < N_NODES) ? dinv[row] : 0.f;
        #pragma unroll
        for (int nt = 0; nt < 4; ++nt)
            H[(size_t)row * 64 + nt * 16 + l16] = f2bf(acc[nt][reg] * di);
    }
}

// ---------------------------------------------------------------- aggregate -
// 4 nodes/block (1/wave). Lane split: g = lane>>4 (row group), q = lane&15
// (col quad). Each gather instruction loads u16x4 (8B) -> one load covers 4
// edges (4 rows x 16 quads). Indices staged in LDS (32 slots/node padded with
// zero row N_NODES). Cross-group combine: shfl_xor(16,32) butterfly.
template <bool GELU>
__global__ __launch_bounds__(256) void k_aggregate(const u16* __restrict__ hs,
                                                   const int* __restrict__ csr_src,
                                                   const int* __restrict__ row_start,
                                                   const float* __restrict__ dinv,
                                                   const float* __restrict__ b,
                                                   void* __restrict__ outraw) {
    __shared__ int sIdx[128];
    __shared__ int sRS[5];
    const int t = threadIdx.x;
    const int n0 = blockIdx.x << 2;
    if (t < 5) sRS[t] = row_start[n0 + t];
    __syncthreads();
    if (t < 128) {
        int k = t >> 5, o = t & 31;
        int jsk = sRS[k];
        int degk = sRS[k + 1] - jsk;
        sIdx[t] = (o < degk) ? csr_src[jsk + o] : N_NODES;   // pad -> zero row
    }
    __syncthreads();

    const int w    = t >> 6;
    const int lane = t & 63;
    const int g    = lane >> 4;     // row group 0..3
    const int q    = lane & 15;     // col quad 0..15
    const int node = n0 + w;
    const int deg  = sRS[w + 1] - sRS[w];
    const u16x4* __restrict__ hs4 = (const u16x4*)hs;   // row = 16 quads

    float a0 = 0.f, a1 = 0.f, a2 = 0.f, a3 = 0.f;
    if (g == 0) {   // self-loop (counted once)
        u16x4 v = hs4[((unsigned)node << 4) + q];
        a0 = bf2f(v[0]); a1 = bf2f(v[1]); a2 = bf2f(v[2]); a3 = bf2f(v[3]);
    }

    if (deg <= 32) {
        const int* myIdx = sIdx + (w << 5);
#define GQ(B) { \
        int r = myIdx[(B) * 4 + g]; \
        u16x4 v = hs4[((unsigned)r << 4) + q]; \
        a0 += bf2f(v[0]); a1 += bf2f(v[1]); a2 += bf2f(v[2]); a3 += bf2f(v[3]); }
        if (deg > 0)  { GQ(0) GQ(1) }
        if (deg > 8)  { GQ(2) GQ(3) }
        if (deg > 16) { GQ(4) GQ(5) }
        if (deg > 24) { GQ(6) GQ(7) }
#undef GQ
    } else {
        const int jS = sRS[w];
        const int jE = sRS[w + 1];
        int j = jS;
        for (; j + 8 <= jE; j += 8) {
            int ra = csr_src[j + g];
            int rb = csr_src[j + 4 + g];
            u16x4 va = hs4[((unsigned)ra << 4) + q];
            u16x4 vb = hs4[((unsigned)rb << 4) + q];
            a0 += bf2f(va[0]); a1 += bf2f(va[1]); a2 += bf2f(va[2]); a3 += bf2f(va[3]);
            a0 += bf2f(vb[0]); a1 += bf2f(vb[1]); a2 += bf2f(vb[2]); a3 += bf2f(vb[3]);
        }
        int rem = jE - j;                 // 0..7
        if (g < rem) {
            int r = csr_src[j + g];
            u16x4 v = hs4[((unsigned)r << 4) + q];
            a0 += bf2f(v[0]); a1 += bf2f(v[1]); a2 += bf2f(v[2]); a3 += bf2f(v[3]);
        }
        if (g + 4 < rem) {
            int r = csr_src[j + 4 + g];
            u16x4 v = hs4[((unsigned)r << 4) + q];
            a0 += bf2f(v[0]); a1 += bf2f(v[1]); a2 += bf2f(v[2]); a3 += bf2f(v[3]);
        }
    }

    // combine the 4 row-groups (lane bits 4,5)
    a0 += __shfl_xor(a0, 16); a1 += __shfl_xor(a1, 16);
    a2 += __shfl_xor(a2, 16); a3 += __shfl_xor(a3, 16);
    a0 += __shfl_xor(a0, 32); a1 += __shfl_xor(a1, 32);
    a2 += __shfl_xor(a2, 32); a3 += __shfl_xor(a3, 32);

    const float di = dinv[node];
    float4 bb = ((const float4*)b)[q];
    float r0 = di * a0 + bb.x;
    float r1 = di * a1 + bb.y;
    float r2 = di * a2 + bb.z;
    float r3 = di * a3 + bb.w;
    if (GELU) {
        r0 = 0.5f * r0 * (1.0f + erff(r0 * 0.70710678118654752f));
        r1 = 0.5f * r1 * (1.0f + erff(r1 * 0.70710678118654752f));
        r2 = 0.5f * r2 * (1.0f + erff(r2 * 0.70710678118654752f));
        r3 = 0.5f * r3 * (1.0f + erff(r3 * 0.70710678118654752f));
        if (g == 0) {
            u16x4 o;
            o[0] = f2bf(r0); o[1] = f2bf(r1); o[2] = f2bf(r2); o[3] = f2bf(r3);
            ((u16x4*)outraw)[((unsigned)node << 4) + q] = o;
        }
    } else {
        if (g == 0)
            ((float4*)outraw)[((unsigned)node << 4) + q] = make_float4(r0, r1, r2, r3);
    }
}

// ---------------------------------------------------------------- launch ----
extern "C" void kernel_launch(void* const* d_in, const int* in_sizes, int n_in,
                              void* d_out, int out_size, void* d_ws, size_t ws_size,
                              hipStream_t stream) {
    const float* x  = (const float*)d_in[0];
    const int* edge = (const int*)d_in[1];           // [2, N_EDGES] int32
    const float* W1 = (const float*)d_in[2];
    const float* b1 = (const float*)d_in[3];
    const float* W2 = (const float*)d_in[4];
    const float* b2 = (const float*)d_in[5];
    float* out = (float*)d_out;                      // [N_NODES, 64] fp32

    const int* src = edge;
    const int* dst = edge + N_EDGES;

    char* ws = (char*)d_ws;
    int*   bucketCursor = (int*)(ws);                 // 196
    int*   gBase        = (int*)(ws + 1024);          // 196
    int*   row_start    = (int*)(ws + 2048);          // N+1
    float* dinv         = (float*)(ws + 402176);      // N
    int*   csr_src      = (int*)(ws + 802304);        // E  (ends 7202304)
    u16*   hsb          = (u16*)(ws + 7202304);       // 100032 rows bf16 (ends 20006400)
    unsigned int* bins  = (unsigned int*)hsb;         // 12.54MB, dead before gemm1
    u16*   out1b        = (u16*)(ws + 20006400);      // 100032 rows bf16

    const int nBlkBin  = (N_EDGES + BINCHUNK - 1) / BINCHUNK;  // 391
    const int nBlkGemm = (N_NODES + 63) / 64;                  // 1563 (covers 100032)
    const int nBlkAgg  = N_NODES / 4;                          // 25000

    // ---- CSR build ----
    hipMemsetAsync(bucketCursor, 0, NBUK * sizeof(int), stream);
    k_bin<<<nBlkBin, 256, 0, stream>>>(src, dst, bucketCursor, bins);
    k_bscan<<<1, 256, 0, stream>>>(bucketCursor, gBase, row_start);
    k_build<<<NBUK, 256, 0, stream>>>(bins, bucketCursor, gBase, row_start, dinv, csr_src);

    // ---- layer 1 ----
    k_gemm1<<<nBlkGemm, 256, 0, stream>>>(x, W1, dinv, hsb);
    k_aggregate<true><<<nBlkAgg, 256, 0, stream>>>(hsb, csr_src, row_start, dinv, b1, out1b);

    // ---- layer 2 ----
    k_gemm2<<<nBlkGemm, 256, 0, stream>>>(out1b, W2, dinv, hsb);
    k_aggregate<false><<<nBlkAgg, 256, 0, stream>>>(hsb, csr_src, row_start, dinv, b2, out);
}